// Round 1
// baseline (246.998 us; speedup 1.0000x reference)
//
#include <hip/hip_runtime.h>
#include <stdint.h>

// Problem constants
#define T_TOK 1024
#define DIN   2048
#define NOUT  8192   // 2*O
#define OSL   4096   // O per slice
#define ROWS_PAD 1408
#define BM 128
#define BN 128
#define BK 32
#define NT (DIN / BK)   // 64 K-steps
#define BUF1 16384      // second LDS buffer base

typedef _Float16 f16x8 __attribute__((ext_vector_type(8)));
typedef _Float16 f16x2 __attribute__((ext_vector_type(2)));
typedef float    f32x4 __attribute__((ext_vector_type(4)));

__device__ __forceinline__ void gload16(const void* gp, void* lp) {
  __builtin_amdgcn_global_load_lds(
      (__attribute__((address_space(1))) void*)gp,
      (__attribute__((address_space(3))) void*)lp, 16, 0, 0);
}

__device__ __forceinline__ f16x2 u2h(uint32_t u) {
  union { uint32_t u; f16x2 h; } c; c.u = u; return c.h;
}

__device__ __forceinline__ f16x8 cvt_interleave(float4 f0, float4 f1) {
  // k-order [0,4,1,5,2,6,3,7] so packed-nibble pairs (n_j, n_{j+4}) line up
  f16x8 h;
  h[0] = (_Float16)f0.x; h[1] = (_Float16)f1.x;
  h[2] = (_Float16)f0.y; h[3] = (_Float16)f1.y;
  h[4] = (_Float16)f0.z; h[5] = (_Float16)f1.z;
  h[6] = (_Float16)f0.w; h[7] = (_Float16)f1.w;
  return h;
}

#define VMCNT5() asm volatile("s_waitcnt vmcnt(5)" ::: "memory")
#define VMCNT0() asm volatile("s_waitcnt vmcnt(0)" ::: "memory")
#define LGKM0()  asm volatile("s_waitcnt lgkmcnt(0)" ::: "memory")

// ============ prep: sort + x->fp16 + wb->fp16 (NO W_eff materialization) ============
// blocks: [0] sort | [1, 1+T_TOK] x rows (last = zero pad row) | rest: wb rows
__global__ void prep(const float* __restrict__ x, const float* __restrict__ wb,
                     const int* __restrict__ indices,
                     _Float16* __restrict__ xh, _Float16* __restrict__ wbh,
                     int* __restrict__ inv, int* __restrict__ meta)
{
  const int b = blockIdx.x;
  const int tid = threadIdx.x;

  if (b == 0) {  // ---- token sort into 128-aligned adapter groups ----
    __shared__ int cnt[4], cur[4];
    if (tid < 4) cnt[tid] = 0;
    __syncthreads();
    for (int t = tid; t < T_TOK; t += 256) atomicAdd(&cnt[indices[t]], 1);
    __syncthreads();
    if (tid == 0) {
      int off = 0;
      for (int a = 0; a < 4; ++a) {
        meta[a] = off;
        meta[5 + a] = off + cnt[a];
        cur[a] = off;
        off = (off + cnt[a] + 127) & ~127;
      }
      meta[4] = off;
    }
    __syncthreads();
    for (int i = tid; i < ROWS_PAD; i += 256) inv[i] = -1;
    __syncthreads();
    for (int t = tid; t < T_TOK; t += 256) {
      int a = indices[t];
      int p = atomicAdd(&cur[a], 1);
      inv[p] = t;
    }
    return;
  }

  if (b <= 1 + T_TOK) {  // ---- x -> fp16, interleaved ----
    const int row = b - 1;          // 0..T_TOK (T_TOK = zero row)
    const int d0 = tid * 8;
    f16x8 h;
    if (row < T_TOK) {
      const float* src = x + (size_t)row * DIN + d0;
      h = cvt_interleave(*(const float4*)src, *(const float4*)(src + 4));
    } else {
#pragma unroll
      for (int j = 0; j < 8; ++j) h[j] = (_Float16)0.0f;
    }
    *(f16x8*)(xh + (size_t)row * DIN + d0) = h;
    return;
  }

  // ---- wb -> fp16 row n, interleaved ----
  const int n = b - (2 + T_TOK);    // 0..NOUT-1
  const int d0 = tid * 8;
  const float* src = wb + (size_t)n * DIN + d0;
  f16x8 v = cvt_interleave(*(const float4*)src, *(const float4*)(src + 4));
  *(f16x8*)(wbh + (size_t)n * DIN + d0) = v;
}

// ============ fused dequant GEMM, depth-2 pipelined (counted vmcnt, raw barriers) ====
// 128x128 tile, BK=32, 4 waves (2x2 of 64x64), 16x16x32 f16 MFMA.
// A staged via global_load_lds (XOR chunk swizzle); B dequantized in-regs -> ds_write.
// Exactly 5 VMEM ops per thread per K-step: 2 gload_lds + 1 int2 + 2 f16x8.
__global__ __launch_bounds__(256) void kfuse(
    const _Float16* __restrict__ xh, const _Float16* __restrict__ wbh,
    const int* __restrict__ qw0, const int* __restrict__ qw1,
    const int* __restrict__ qz0, const int* __restrict__ qz1,
    const float* __restrict__ sc0, const float* __restrict__ sc1,
    const float* __restrict__ bias,
    const int* __restrict__ inv, const int* __restrict__ meta,
    float* __restrict__ out)
{
  // XCD-bijective swizzle (704 = 8*88): xcd = id%8 owns n-tiles [xcd*8, xcd*8+8)
  // across ALL m-tiles -> its 4MB wbh slice stays L2-resident for the m-sweep.
  const int id = blockIdx.y * 64 + blockIdx.x;            // dispatch-linear, 0..703
  const int m0 = (id >> 6) * BM;
  const int n0 = (((id & 7) << 3) | ((id >> 3) & 7)) * BN;

  if (m0 >= meta[4]) return;
  int ad = 0;
  if (m0 >= meta[1]) ad = 1;
  if (m0 >= meta[2]) ad = 2;
  if (m0 >= meta[3]) ad = 3;
  if (m0 >= meta[5 + ad]) return;      // tile entirely pad

  const int sl = n0 >> 12;
  const int tid  = threadIdx.x;
  const int wave = tid >> 6;
  const int lane = tid & 63;
  const int quad = lane >> 4;
  const int l16  = lane & 15;
  const int wm = (wave & 1) << 6;
  const int wn = (wave >> 1) << 6;

  __shared__ __align__(16) char smem[32768];  // buf0 [0,16K), buf1 [16K,32K); per buf: A[0,8K) B[8K,16K)

  f32x4 acc[4][4];
#pragma unroll
  for (int i = 0; i < 4; ++i)
#pragma unroll
    for (int j = 0; j < 4; ++j) acc[i][j] = (f32x4)0.0f;

  // A staging: staged chunk (tid&3) holds source chunk (tid&3)^((row>>1)&3)
  const int kch = (((tid & 3) ^ ((tid >> 3) & 3)) << 3);
  const int rloc = tid >> 2;
  int r0 = inv[m0 + rloc];       if (r0 < 0) r0 = T_TOK;   // pad -> zero row
  int r1 = inv[m0 + rloc + 64];  if (r1 < 0) r1 = T_TOK;
  const _Float16* ag0 = xh + (size_t)r0 * DIN + kch;
  const _Float16* ag1 = xh + (size_t)r1 * DIN + kch;
  const int saoff0 = wave * 1024;
  const int saoff1 = 4096 + wave * 1024;

  // B dequant setup: thread -> row o_local, k-half (tid&1)
  const int o_local = tid >> 1;
  const int o = n0 + o_local;
  const int o_sl = o & (OSL - 1);
  const int* qwp = (sl ? qw1 : qw0) + ((size_t)ad * OSL + o_sl) * (DIN / 8) + ((tid & 1) << 1);
  const int zw = (sl ? qz1 : qz0)[ad * (OSL / 8) + (o_sl >> 3)];
  const float s = (sl ? sc1 : sc0)[(size_t)ad * OSL + o_sl];
  const int z = (zw >> ((o_sl & 7) << 2)) & 0xF;
  f16x2 s2; s2[0] = s2[1] = (_Float16)s;
  f16x2 k2; k2[0] = k2[1] = (_Float16)(float)(-(1024 + z));
  const _Float16* wbp = wbh + (size_t)o * DIN + ((tid & 1) << 4);

  const int bswz = (o_local >> 1) & 3;
  const int bwoff0 = 8192 + o_local * 64 + (((((tid & 1) << 1)    ) ^ bswz) << 4);
  const int bwoff1 = 8192 + o_local * 64 + (((((tid & 1) << 1) | 1) ^ bswz) << 4);
  const int qoff = ((quad ^ ((l16 >> 1) & 3)) << 4);

  auto LOADREGS = [&](int t, int2 &qv, f16x8 &wa, f16x8 &wb2) {
    qv  = *(const int2*)(qwp + t * 4);
    wa  = *(const f16x8*)(wbp + t * BK);
    wb2 = *(const f16x8*)(wbp + t * BK + 8);
  };
  auto GLOADS = [&](int bb, int t) {
    gload16(ag0 + t * BK, smem + bb + saoff0);
    gload16(ag1 + t * BK, smem + bb + saoff1);
  };
  auto DEQW = [&](int bb, int2 qv, f16x8 wa, f16x8 wb2) {
    const uint32_t wx = (uint32_t)qv.x, wy = (uint32_t)qv.y;
    union U { f16x8 v; f16x2 p[4]; } A_, B_, h0, h1;
    A_.v = wa; B_.v = wb2;
#pragma unroll
    for (int j = 0; j < 4; ++j) {
      uint32_t t0 = ((wx >> (4 * j)) & 0x000F000Fu) | 0x64006400u;
      uint32_t t1 = ((wy >> (4 * j)) & 0x000F000Fu) | 0x64006400u;
      h0.p[j] = (u2h(t0) + k2) * s2 + A_.p[j];
      h1.p[j] = (u2h(t1) + k2) * s2 + B_.p[j];
    }
    *(f16x8*)(smem + bb + bwoff0) = h0.v;
    *(f16x8*)(smem + bb + bwoff1) = h1.v;
  };
  auto COMPUTE = [&](int bb) {
    f16x8 af[4], bf[4];
#pragma unroll
    for (int t = 0; t < 4; ++t)
      af[t] = *(const f16x8*)(smem + bb + (wm + t * 16 + l16) * 64 + qoff);
#pragma unroll
    for (int t = 0; t < 4; ++t)
      bf[t] = *(const f16x8*)(smem + bb + 8192 + (wn + t * 16 + l16) * 64 + qoff);
    __builtin_amdgcn_s_setprio(1);
#pragma unroll
    for (int mt = 0; mt < 4; ++mt)
#pragma unroll
      for (int nt = 0; nt < 4; ++nt)
        acc[mt][nt] = __builtin_amdgcn_mfma_f32_16x16x32_f16(af[mt], bf[nt], acc[mt][nt], 0, 0, 0);
    __builtin_amdgcn_s_setprio(0);
  };

  int2 qvA, qvB;
  f16x8 waA, wbA2, waB, wbB2;

  // prologue: tiles 0 and 1 in flight; ready tile 0
  LOADREGS(0, qvA, waA, wbA2);
  GLOADS(0, 0);
  LOADREGS(1, qvB, waB, wbB2);
  GLOADS(BUF1, 1);
  VMCNT5();                              // tile0 loads done; tile1's 5 in flight
  __builtin_amdgcn_sched_barrier(0);
  DEQW(0, qvA, waA, wbA2);
  LGKM0();
  __builtin_amdgcn_s_barrier();

  // main loop: compute t / t+1, issue t+2 / t+3, ready t+1 / t+2
  for (int t = 0; t < NT - 2; t += 2) {
    LOADREGS(t + 2, qvA, waA, wbA2);     // issue early: hides under COMPUTE
    COMPUTE(0);                           // tile t
    __builtin_amdgcn_s_barrier();         // all waves done reading buf0
    __builtin_amdgcn_sched_barrier(0);
    GLOADS(0, t + 2);                     // overwrite buf0.A
    VMCNT5();                             // tile t+1's loads retired (5 newest = t+2's)
    __builtin_amdgcn_sched_barrier(0);
    DEQW(BUF1, qvB, waB, wbB2);           // B(t+1) -> buf1
    LGKM0();
    __builtin_amdgcn_s_barrier();         // buf1 = tile t+1 ready

    LOADREGS(t + 3, qvB, waB, wbB2);
    COMPUTE(BUF1);                        // tile t+1
    __builtin_amdgcn_s_barrier();
    __builtin_amdgcn_sched_barrier(0);
    GLOADS(BUF1, t + 3);
    VMCNT5();
    __builtin_amdgcn_sched_barrier(0);
    DEQW(0, qvA, waA, wbA2);              // B(t+2) -> buf0
    LGKM0();
    __builtin_amdgcn_s_barrier();         // buf0 = tile t+2 ready
  }

  // epilogue: tiles NT-2, NT-1
  COMPUTE(0);                             // tile 62
  VMCNT0();
  __builtin_amdgcn_sched_barrier(0);
  DEQW(BUF1, qvB, waB, wbB2);             // B(63)
  LGKM0();
  __builtin_amdgcn_s_barrier();
  COMPUTE(BUF1);                          // tile 63

  // C/D: col=lane&15, row=quad*4+reg; scatter to out[token], +bias
#pragma unroll
  for (int mt = 0; mt < 4; ++mt) {
    const int rowb = m0 + wm + mt * 16 + quad * 4;
    int tk[4];
#pragma unroll
    for (int r = 0; r < 4; ++r) tk[r] = inv[rowb + r];
#pragma unroll
    for (int nt = 0; nt < 4; ++nt) {
      const int col = n0 + wn + nt * 16 + l16;
      const float bv = bias[col];
#pragma unroll
      for (int r = 0; r < 4; ++r) {
        if (tk[r] >= 0)
          out[(size_t)tk[r] * NOUT + col] = acc[mt][nt][r] + bv;
      }
    }
  }
}

extern "C" void kernel_launch(void* const* d_in, const int* in_sizes, int n_in,
                              void* d_out, int out_size, void* d_ws, size_t ws_size,
                              hipStream_t stream) {
  const float* x    = (const float*)d_in[0];
  const float* wb   = (const float*)d_in[1];
  const float* bias = (const float*)d_in[2];
  const int*   qw0  = (const int*)d_in[3];
  const int*   qw1  = (const int*)d_in[4];
  const int*   qz0  = (const int*)d_in[5];
  const int*   qz1  = (const int*)d_in[6];
  const float* sc0  = (const float*)d_in[7];
  const float* sc1  = (const float*)d_in[8];
  const int*   indices = (const int*)d_in[11];
  float* out = (float*)d_out;

  // workspace: xh [(T_TOK+1)*DIN f16] | inv | meta | wbh [NOUT*DIN f16] (~36.5 MB)
  char* w = (char*)d_ws;
  _Float16* xh = (_Float16*)w;
  size_t off = (size_t)(T_TOK + 1) * DIN * 2;
  int* inv  = (int*)(w + off);
  int* meta = inv + ROWS_PAD;
  size_t woff = (off + (size_t)ROWS_PAD * 4 + 64 + 255) & ~(size_t)255;
  _Float16* wbh = (_Float16*)(w + woff);

  prep<<<2 + T_TOK + NOUT, 256, 0, stream>>>(x, wb, indices, xh, wbh, inv, meta);
  kfuse<<<dim3(64, 11), 256, 0, stream>>>(xh, wbh, qw0, qw1, qz0, qz1, sc0, sc1,
                                          bias, inv, meta, out);
}